// Round 22
// baseline (66.059 us; speedup 1.0000x reference)
//
#include <hip/hip_runtime.h>
#include <hip/hip_bf16.h>

typedef unsigned short u16;
typedef short s8v __attribute__((ext_vector_type(8)));
typedef float f4v __attribute__((ext_vector_type(4)));
typedef u16 u16x8 __attribute__((ext_vector_type(8)));

static __device__ __forceinline__ u16 f2bf(float v) {
    __hip_bfloat16 h = __float2bfloat16(v);
    return *(u16*)&h;
}

// ---------------------------------------------------------------------------
// Dispatch 1: weight prep only (tiny, ~2us).
//  b in [0,1152): Wt1 transpose.  b in [1152,1920): Wt2 transpose.
// Wt[f][kc*DIN + d] = bf16(w[f][d][kc]);  w is [256][DIN][3]
// ---------------------------------------------------------------------------
__global__ __launch_bounds__(256) void prep_kernel(
    const float* __restrict__ w1,
    const float* __restrict__ w2,
    u16* __restrict__ Wt1,
    u16* __restrict__ Wt2)
{
    const int b = blockIdx.x, tid = threadIdx.x;
    if (b < 1152) {
        const int K = 1152, DIN = 384;
        int e = b * 256 + tid;
        int f = e / K;
        int rem = e - f * K;
        int kc = rem / DIN;
        int d = rem - kc * DIN;
        Wt1[e] = f2bf(w1[f * K + d * 3 + kc]);
    } else {
        const int K = 768, DIN = 256;
        int e = (b - 1152) * 256 + tid;
        int f = e / K;
        int rem = e - f * K;
        int kc = rem / DIN;
        int d = rem - kc * DIN;
        Wt2[e] = f2bf(w2[f * K + d * 3 + kc]);
    }
}

// ---------------------------------------------------------------------------
// Dispatch 2: role-merged.
//  blocks [0,512):    FUSED conv1 -> LN1/ReLU -> h1(LDS) -> conv2 -> dot
//                     (R21 best-verified body, XCD-swizzled).
//  blocks [512,1536): LR gather (R21 body, XCD-batch grouped; LDS aliased).
// Dispatch-order packing: conv blocks occupy all CUs (2/CU) first; gather
// blocks backfill as conv blocks retire -> gather's HBM stream overlaps the
// conv tail (complementary pipes; conv FETCH is only 16MB total).
// LDS 62464 B, __launch_bounds__(256,2) -> 2 blocks/CU for both roles.
// ---------------------------------------------------------------------------
__global__ __launch_bounds__(256, 2) void conv_gather_kernel(
    const float* __restrict__ x,
    const int*   __restrict__ target,
    const u16* __restrict__ Wt1,   // [256][1152]
    const u16* __restrict__ Wt2,   // [256][768]
    const float* __restrict__ cb1, const float* __restrict__ g1,
    const float* __restrict__ bb1,
    const float* __restrict__ cb2, const float* __restrict__ g2,
    const float* __restrict__ bb2,
    const float* __restrict__ lw, const float* __restrict__ lbp,
    float* __restrict__ out0,
    float* __restrict__ dpo)
{
    __shared__ __align__(128) char LDS[62464];
    const int tid = threadIdx.x;

    if (blockIdx.x >= 512) {
        // ================= gather role (R21 body) =================
        int* c    = (int*)LDS;             // 512 ints
        int* ridx = (int*)(LDS + 2048);    // 64 ints
        const int rid = blockIdx.x - 512;
        const int xcd = rid & 7, i = rid >> 3;
        const int n = xcd * 4 + (i >> 5), sub = i & 31;
        c[tid]       = target[n * 512 + tid];
        c[tid + 256] = target[n * 512 + 256 + tid];
        __syncthreads();
        for (int off = 1; off < 512; off <<= 1) {
            int v0 = (tid       >= off) ? c[tid       - off] : 0;
            int v1 = (tid + 256 >= off) ? c[tid + 256 - off] : 0;
            __syncthreads();
            c[tid]       += v0;
            c[tid + 256] += v1;
            __syncthreads();
        }
        const int total = c[511];
        if (tid < 64) {
            int t = sub * 64 + tid;
            int lo = 0, hi = 512;
            while (lo < hi) {
                int mid = (lo + hi) >> 1;
                if (c[mid] <= t) lo = mid + 1; else hi = mid;
            }
            ridx[tid] = (t < total) ? min(lo, 511) : -1;
        }
        __syncthreads();

        const size_t xbase = (size_t)(n << 9) * 384;
        const size_t obase = ((size_t)(n << 11) + sub * 64) * 384;
        #pragma unroll 4
        for (int it = 0; it < 12; ++it) {
            int u  = tid + it * 256;
            int j  = u % 48;
            int rl = u / 48;
            int ie = ridx[rl];
            f4v v0 = {0.f, 0.f, 0.f, 0.f}, v1 = v0;
            if (ie >= 0) {
                const float* src = &x[xbase + (size_t)ie * 384];
                v0 = *(const f4v*)&src[j * 4];
                v1 = *(const f4v*)&src[(j + 48) * 4];
            }
            float* dst = &out0[obase + (size_t)rl * 384];
            __builtin_nontemporal_store(v0, (f4v*)&dst[j * 4]);
            __builtin_nontemporal_store(v1, (f4v*)&dst[(j + 48) * 4]);
        }
        return;
    }

    // ================= conv role (R21/R17 best-verified body) =================
    char* Bs    = LDS + 27648;             // 32 KB
    float* redS = (float*)(LDS + 60416);   // [48*4]
    float* redQ = (float*)(LDS + 61184);   // [48*4]
    float* redP = (float*)(LDS + 61952);   // [32*4]

    const int lane = tid & 63, wc = tid >> 6;
    const int lr = lane & 15, q4 = lane >> 4;
    const int sb = (blockIdx.x & 7) * 64 + (blockIdx.x >> 3);
    const int m0 = sb * 32;
    const int n  = m0 >> 9, l0 = m0 & 511;

    const int b_r    = tid >> 3;
    const int b_slot = (tid & 7) ^ (b_r & 7);
    int boff[4];
    #pragma unroll
    for (int ni = 0; ni < 4; ni++) boff[ni] = (64 * wc + 16 * ni + lr) * 128;
    const int slot0 = ((q4)     ^ (lr & 7)) << 4;
    const int slot1 = ((q4 | 4) ^ (lr & 7)) << 4;

    auto loadB = [&](const u16* __restrict__ Wt, int K, int t, s8v* bv) {
        const int k0 = t * 64;
        const u16* bsrc = Wt + (size_t)b_r * K + k0 + b_slot * 8;
        #pragma unroll
        for (int q = 0; q < 8; q++)
            bv[q] = *(const s8v*)(bsrc + (size_t)q * 32 * K);
    };
    auto writeB = [&](const s8v* bv) {
        #pragma unroll
        for (int q = 0; q < 8; q++)
            *(s8v*)(Bs + q * 4096 + tid * 16) = bv[q];
    };

    for (int u = tid; u < 1728; u += 256) {          // 36 rows x 48 slots
        int j7 = u / 48, s = u - j7 * 48;
        int lp = l0 - 2 + j7;
        f4v v0 = {0.f, 0.f, 0.f, 0.f}, v1 = v0;
        if (lp >= 0 && lp < 512) {
            const float* src = x + ((size_t)((n << 9) + lp)) * 384 + s * 8;
            v0 = *(const f4v*)src;
            v1 = *(const f4v*)(src + 4);
        }
        u16x8 r;
        #pragma unroll
        for (int jj = 0; jj < 4; jj++) { r[jj] = f2bf(v0[jj]); r[4 + jj] = f2bf(v1[jj]); }
        int ss = (s & ~7) | ((s & 7) ^ (j7 & 7));
        *(u16x8*)(LDS + j7 * 768 + ss * 16) = r;
    }

    auto xwread = [&](int j, int s) -> s8v {
        int j7 = min(max(j, 7), 42) - 7;
        int ss = (s & ~7) | ((s & 7) ^ (j7 & 7));
        return *(const s8v*)(LDS + j7 * 768 + (ss << 4));
    };

    // ================= P1: conv1, 18 BK=64 steps ==========================
    f4v acc[3][4];
    #pragma unroll
    for (int mi = 0; mi < 3; mi++)
        #pragma unroll
        for (int ni = 0; ni < 4; ni++) acc[mi][ni] = {0.f, 0.f, 0.f, 0.f};

    {
        s8v bv[8];
        loadB(Wt1, 1152, 0, bv);
        writeB(bv);
    }
    __syncthreads();

    for (int t = 0; t < 18; ++t) {
        s8v nv[8];
        const bool pre = (t + 1 < 18);
        if (pre) loadB(Wt1, 1152, t + 1, nv);
        {
            const int k0 = t * 64;
            const int kc = k0 / 384;
            const int s0 = (k0 - kc * 384) >> 3;
            #pragma unroll
            for (int kk = 0; kk < 2; kk++) {
                const int sl = kk ? slot1 : slot0;
                const int s  = s0 + 4 * kk + q4;
                s8v a0 = xwread(lr + kc,      s);
                s8v a1 = xwread(16 + lr + kc, s);
                s8v a2 = xwread(32 + lr + kc, s);
                s8v b0 = *(const s8v*)(Bs + boff[0] + sl);
                s8v b1 = *(const s8v*)(Bs + boff[1] + sl);
                s8v b2 = *(const s8v*)(Bs + boff[2] + sl);
                s8v b3 = *(const s8v*)(Bs + boff[3] + sl);
                acc[0][0] = __builtin_amdgcn_mfma_f32_16x16x32_bf16(a0, b0, acc[0][0], 0, 0, 0);
                acc[0][1] = __builtin_amdgcn_mfma_f32_16x16x32_bf16(a0, b1, acc[0][1], 0, 0, 0);
                acc[0][2] = __builtin_amdgcn_mfma_f32_16x16x32_bf16(a0, b2, acc[0][2], 0, 0, 0);
                acc[0][3] = __builtin_amdgcn_mfma_f32_16x16x32_bf16(a0, b3, acc[0][3], 0, 0, 0);
                acc[1][0] = __builtin_amdgcn_mfma_f32_16x16x32_bf16(a1, b0, acc[1][0], 0, 0, 0);
                acc[1][1] = __builtin_amdgcn_mfma_f32_16x16x32_bf16(a1, b1, acc[1][1], 0, 0, 0);
                acc[1][2] = __builtin_amdgcn_mfma_f32_16x16x32_bf16(a1, b2, acc[1][2], 0, 0, 0);
                acc[1][3] = __builtin_amdgcn_mfma_f32_16x16x32_bf16(a1, b3, acc[1][3], 0, 0, 0);
                acc[2][0] = __builtin_amdgcn_mfma_f32_16x16x32_bf16(a2, b0, acc[2][0], 0, 0, 0);
                acc[2][1] = __builtin_amdgcn_mfma_f32_16x16x32_bf16(a2, b1, acc[2][1], 0, 0, 0);
                acc[2][2] = __builtin_amdgcn_mfma_f32_16x16x32_bf16(a2, b2, acc[2][2], 0, 0, 0);
                acc[2][3] = __builtin_amdgcn_mfma_f32_16x16x32_bf16(a2, b3, acc[2][3], 0, 0, 0);
            }
        }
        __syncthreads();
        if (pre) {
            writeB(nv);
            __syncthreads();
        }
    }

    // ---- P1 epilogue: bias + LN1 + ReLU -> h1 LDS (34 rows, over xw) ----
    int col[4];
    float cbv[4], gv[4], bbv[4];
    #pragma unroll
    for (int ni = 0; ni < 4; ni++) {
        col[ni] = 64 * wc + 16 * ni + lr;
        cbv[ni] = cb1[col[ni]]; gv[ni] = g1[col[ni]]; bbv[ni] = bb1[col[ni]];
    }

    #pragma unroll
    for (int mi = 0; mi < 3; mi++)
        #pragma unroll
        for (int reg = 0; reg < 4; reg++) {
            float s = 0.f, q = 0.f;
            #pragma unroll
            for (int ni = 0; ni < 4; ni++) {
                float v = acc[mi][ni][reg] + cbv[ni];
                s += v; q += v * v;
            }
            #pragma unroll
            for (int msk = 1; msk < 16; msk <<= 1) {
                s += __shfl_xor(s, msk);
                q += __shfl_xor(q, msk);
            }
            if (lr == 0) {
                int rl = 16 * mi + 4 * q4 + reg;
                redS[rl * 4 + wc] = s;
                redQ[rl * 4 + wc] = q;
            }
        }
    __syncthreads();

    #pragma unroll
    for (int mi = 0; mi < 3; mi++)
        #pragma unroll
        for (int reg = 0; reg < 4; reg++) {
            int rl = 16 * mi + 4 * q4 + reg;
            int h  = rl - 7;
            if (h >= 0 && h < 34) {
                float4 ps = *(float4*)&redS[rl * 4];
                float4 pq = *(float4*)&redQ[rl * 4];
                float mean = (ps.x + ps.y + ps.z + ps.w) * (1.f / 256.f);
                float var  = (pq.x + pq.y + pq.z + pq.w) * (1.f / 256.f) - mean * mean;
                float rs   = rsqrtf(var + 1e-5f);
                int l = l0 - 8 + rl;
                bool lv = (l >= 0 && l < 512);
                #pragma unroll
                for (int ni = 0; ni < 4; ni++) {
                    float v = acc[mi][ni][reg] + cbv[ni];
                    float o = lv ? fmaxf(0.f, (v - mean) * rs * gv[ni] + bbv[ni]) : 0.f;
                    int slot = (col[ni] >> 3) ^ (h & 7);
                    *(u16*)(LDS + h * 512 + slot * 16 + (col[ni] & 7) * 2) = f2bf(o);
                }
            }
        }

    // ================= P2: conv2 (A from h1 LDS), 12 BK=64 steps ==========
    f4v acc2[2][4];
    #pragma unroll
    for (int mi = 0; mi < 2; mi++)
        #pragma unroll
        for (int ni = 0; ni < 4; ni++) acc2[mi][ni] = {0.f, 0.f, 0.f, 0.f};

    {
        s8v bv[8];
        loadB(Wt2, 768, 0, bv);
        writeB(bv);
    }
    __syncthreads();

    for (int t2 = 0; t2 < 12; ++t2) {
        s8v nv[8];
        const bool pre = (t2 + 1 < 12);
        if (pre) loadB(Wt2, 768, t2 + 1, nv);
        {
            const int kc2   = t2 >> 2;
            const int sbase = 8 * (t2 & 3);
            #pragma unroll
            for (int kk = 0; kk < 2; kk++) {
                const int sl = kk ? slot1 : slot0;
                s8v b0 = *(const s8v*)(Bs + boff[0] + sl);
                s8v b1 = *(const s8v*)(Bs + boff[1] + sl);
                s8v b2 = *(const s8v*)(Bs + boff[2] + sl);
                s8v b3 = *(const s8v*)(Bs + boff[3] + sl);
                s8v a0, a1;
                {
                    int h = lr + kc2;
                    int s = sbase + 4 * kk + q4;
                    a0 = *(const s8v*)(LDS + h * 512 + ((s ^ (h & 7)) << 4));
                    h = 16 + lr + kc2;
                    a1 = *(const s8v*)(LDS + h * 512 + ((s ^ (h & 7)) << 4));
                }
                acc2[0][0] = __builtin_amdgcn_mfma_f32_16x16x32_bf16(a0, b0, acc2[0][0], 0, 0, 0);
                acc2[0][1] = __builtin_amdgcn_mfma_f32_16x16x32_bf16(a0, b1, acc2[0][1], 0, 0, 0);
                acc2[0][2] = __builtin_amdgcn_mfma_f32_16x16x32_bf16(a0, b2, acc2[0][2], 0, 0, 0);
                acc2[0][3] = __builtin_amdgcn_mfma_f32_16x16x32_bf16(a0, b3, acc2[0][3], 0, 0, 0);
                acc2[1][0] = __builtin_amdgcn_mfma_f32_16x16x32_bf16(a1, b0, acc2[1][0], 0, 0, 0);
                acc2[1][1] = __builtin_amdgcn_mfma_f32_16x16x32_bf16(a1, b1, acc2[1][1], 0, 0, 0);
                acc2[1][2] = __builtin_amdgcn_mfma_f32_16x16x32_bf16(a1, b2, acc2[1][2], 0, 0, 0);
                acc2[1][3] = __builtin_amdgcn_mfma_f32_16x16x32_bf16(a1, b3, acc2[1][3], 0, 0, 0);
            }
        }
        __syncthreads();
        if (pre) {
            writeB(nv);
            __syncthreads();
        }
    }

    // ---- P2 epilogue: bias + LN2 + ReLU + dot(lin_w) -> dpo ----
    float cbv2[4], gv2[4], bbv2[4], lwv[4];
    #pragma unroll
    for (int ni = 0; ni < 4; ni++) {
        cbv2[ni] = cb2[col[ni]]; gv2[ni] = g2[col[ni]]; bbv2[ni] = bb2[col[ni]];
        lwv[ni]  = lw[col[ni]];
    }

    float sv[2][4], sq[2][4];
    #pragma unroll
    for (int mi = 0; mi < 2; mi++)
        #pragma unroll
        for (int reg = 0; reg < 4; reg++) {
            float s = 0.f, q = 0.f;
            #pragma unroll
            for (int ni = 0; ni < 4; ni++) {
                float v = acc2[mi][ni][reg] + cbv2[ni];
                s += v; q += v * v;
            }
            #pragma unroll
            for (int msk = 1; msk < 16; msk <<= 1) {
                s += __shfl_xor(s, msk);
                q += __shfl_xor(q, msk);
            }
            sv[mi][reg] = s; sq[mi][reg] = q;
        }
    __syncthreads();
    if (lr == 0) {
        #pragma unroll
        for (int mi = 0; mi < 2; mi++)
            #pragma unroll
            for (int reg = 0; reg < 4; reg++) {
                int rl = 16 * mi + 4 * q4 + reg;
                redS[rl * 4 + wc] = sv[mi][reg];
                redQ[rl * 4 + wc] = sq[mi][reg];
            }
    }
    __syncthreads();

    float pp[2][4];
    #pragma unroll
    for (int mi = 0; mi < 2; mi++)
        #pragma unroll
        for (int reg = 0; reg < 4; reg++) {
            int rl = 16 * mi + 4 * q4 + reg;
            float4 ps = *(float4*)&redS[rl * 4];
            float4 pq = *(float4*)&redQ[rl * 4];
            float mean = (ps.x + ps.y + ps.z + ps.w) * (1.f / 256.f);
            float var  = (pq.x + pq.y + pq.z + pq.w) * (1.f / 256.f) - mean * mean;
            float rs   = rsqrtf(var + 1e-5f);
            float p = 0.f;
            #pragma unroll
            for (int ni = 0; ni < 4; ni++) {
                float v = acc2[mi][ni][reg] + cbv2[ni];
                float o = fmaxf(0.f, (v - mean) * rs * gv2[ni] + bbv2[ni]);
                p += o * lwv[ni];
            }
            #pragma unroll
            for (int msk = 1; msk < 16; msk <<= 1) p += __shfl_xor(p, msk);
            pp[mi][reg] = p;
        }
    if (lr == 0) {
        #pragma unroll
        for (int mi = 0; mi < 2; mi++)
            #pragma unroll
            for (int reg = 0; reg < 4; reg++) {
                int rl = 16 * mi + 4 * q4 + reg;
                redP[rl * 4 + wc] = pp[mi][reg];
            }
    }
    __syncthreads();
    if (tid < 32) {
        float4 p4 = *(float4*)&redP[tid * 4];
        dpo[m0 + tid] = p4.x + p4.y + p4.z + p4.w + lbp[0];
    }
}

// ---------------------------------------------------------------------------
extern "C" void kernel_launch(void* const* d_in, const int* in_sizes, int n_in,
                              void* d_out, int out_size, void* d_ws, size_t ws_size,
                              hipStream_t stream) {
    const float* x   = (const float*)d_in[0];
    const float* w1  = (const float*)d_in[1];
    const float* b1  = (const float*)d_in[2];
    const float* g1  = (const float*)d_in[3];
    const float* bb1 = (const float*)d_in[4];
    const float* w2  = (const float*)d_in[5];
    const float* b2  = (const float*)d_in[6];
    const float* g2  = (const float*)d_in[7];
    const float* bb2 = (const float*)d_in[8];
    const float* lw  = (const float*)d_in[9];
    const float* lb  = (const float*)d_in[10];
    const int* target = (const int*)d_in[11];

    // ws layout (bytes): Wt1 589824 | Wt2 393216
    char* wsb = (char*)d_ws;
    u16*  Wt1 = (u16*)wsb;
    u16*  Wt2 = (u16*)(wsb + 589824);

    float* out0 = (float*)d_out;                  // [32, 2048, 384]
    float* dpo  = out0 + (size_t)32 * 2048 * 384; // [32, 512]

    // D1: weight prep (tiny)
    prep_kernel<<<1920, 256, 0, stream>>>(w1, w2, Wt1, Wt2);

    // D2: conv blocks [0,512) + gather blocks [512,1536) — gather backfills
    // CUs as conv blocks retire (overlap of HBM stream with conv tail).
    conv_gather_kernel<<<1536, 256, 0, stream>>>(
        x, target, Wt1, Wt2, b1, g1, bb1, b2, g2, bb2, lw, lb, out0, dpo);
}

// Round 23
// 64.855 us; speedup vs baseline: 1.0186x; 1.0186x over previous
//
#include <hip/hip_runtime.h>
#include <hip/hip_bf16.h>

typedef unsigned short u16;
typedef short s8v __attribute__((ext_vector_type(8)));
typedef float f4v __attribute__((ext_vector_type(4)));
typedef u16 u16x8 __attribute__((ext_vector_type(8)));

static __device__ __forceinline__ u16 f2bf(float v) {
    __hip_bfloat16 h = __float2bfloat16(v);
    return *(u16*)&h;
}

// ---------------------------------------------------------------------------
// Dispatch 1: gather + weight prep (no cross-block deps).
//  b in [0,1024):    gather role. XCD-batch grouping: xcd=b&7, i=b>>3,
//                    n = xcd*4 + (i>>5), sub = i&31  (bijective) -> each
//                    batch's 32 blocks share one XCD L2 (4 batches = 3MB).
//  b in [1024,2176): Wt1 transpose.  b in [2176,2944): Wt2 transpose.
// Wt[f][kc*DIN + d] = bf16(w[f][d][kc]);  w is [256][DIN][3]
// ---------------------------------------------------------------------------
__global__ __launch_bounds__(256) void gather_prep_kernel(
    const float* __restrict__ x,
    const int*   __restrict__ target,
    const float* __restrict__ w1,
    const float* __restrict__ w2,
    u16* __restrict__ Wt1,
    u16* __restrict__ Wt2,
    float* __restrict__ out0)
{
    __shared__ int c[512];
    __shared__ int ridx[64];
    const int b = blockIdx.x, tid = threadIdx.x;

    if (b >= 1024) {
        if (b < 2176) {
            const int K = 1152, DIN = 384;
            int e = (b - 1024) * 256 + tid;
            int f = e / K;
            int rem = e - f * K;
            int kc = rem / DIN;
            int d = rem - kc * DIN;
            Wt1[e] = f2bf(w1[f * K + d * 3 + kc]);
        } else {
            const int K = 768, DIN = 256;
            int e = (b - 2176) * 256 + tid;
            int f = e / K;
            int rem = e - f * K;
            int kc = rem / DIN;
            int d = rem - kc * DIN;
            Wt2[e] = f2bf(w2[f * K + d * 3 + kc]);
        }
        return;
    }

    // ---- gather role (XCD-batch grouped) ----
    const int xcd = b & 7, i = b >> 3;
    const int n = xcd * 4 + (i >> 5), sub = i & 31;
    c[tid]       = target[n * 512 + tid];
    c[tid + 256] = target[n * 512 + 256 + tid];
    __syncthreads();
    for (int off = 1; off < 512; off <<= 1) {
        int v0 = (tid       >= off) ? c[tid       - off] : 0;
        int v1 = (tid + 256 >= off) ? c[tid + 256 - off] : 0;
        __syncthreads();
        c[tid]       += v0;
        c[tid + 256] += v1;
        __syncthreads();
    }
    const int total = c[511];
    if (tid < 64) {
        int t = sub * 64 + tid;
        int lo = 0, hi = 512;
        while (lo < hi) {
            int mid = (lo + hi) >> 1;
            if (c[mid] <= t) lo = mid + 1; else hi = mid;
        }
        ridx[tid] = (t < total) ? min(lo, 511) : -1;
    }
    __syncthreads();

    const size_t xbase = (size_t)(n << 9) * 384;
    const size_t obase = ((size_t)(n << 11) + sub * 64) * 384;
    #pragma unroll 4
    for (int it = 0; it < 12; ++it) {
        int u  = tid + it * 256;
        int j  = u % 48;
        int rl = u / 48;
        int ie = ridx[rl];
        f4v v0 = {0.f, 0.f, 0.f, 0.f}, v1 = v0;
        if (ie >= 0) {
            const float* src = &x[xbase + (size_t)ie * 384];
            v0 = *(const f4v*)&src[j * 4];
            v1 = *(const f4v*)&src[(j + 48) * 4];
        }
        float* dst = &out0[obase + (size_t)rl * 384];
        __builtin_nontemporal_store(v0, (f4v*)&dst[j * 4]);
        __builtin_nontemporal_store(v1, (f4v*)&dst[(j + 48) * 4]);
    }
}

// ---------------------------------------------------------------------------
// Dispatch 2: FUSED conv1 -> LN1/ReLU -> h1(LDS) -> conv2 -> LN2/ReLU -> dot
// Best-verified structure (R17/R21, 64.95us): xw-resident A (36 rows), BK=64
// single-buffered B in LDS with T14 reg-staged async split (loads issued
// before compute, ds_write after barrier).  LDS 62464 B -> 2 blocks/CU.
// 512 blocks XCD-swizzled, 256 thr = 4 waves.
// ---------------------------------------------------------------------------
__global__ __launch_bounds__(256, 2) void fused_conv_kernel(
    const float* __restrict__ x,
    const u16* __restrict__ Wt1,   // [256][1152]
    const u16* __restrict__ Wt2,   // [256][768]
    const float* __restrict__ cb1, const float* __restrict__ g1,
    const float* __restrict__ bb1,
    const float* __restrict__ cb2, const float* __restrict__ g2,
    const float* __restrict__ bb2,
    const float* __restrict__ lw, const float* __restrict__ lbp,
    float* __restrict__ dpo)
{
    __shared__ __align__(128) char LDS[62464];
    char* Bs    = LDS + 27648;             // 32 KB
    float* redS = (float*)(LDS + 60416);   // [48*4]
    float* redQ = (float*)(LDS + 61184);   // [48*4]
    float* redP = (float*)(LDS + 61952);   // [32*4]

    const int tid  = threadIdx.x;
    const int lane = tid & 63, wc = tid >> 6;
    const int lr = lane & 15, q4 = lane >> 4;
    const int sb = (blockIdx.x & 7) * 64 + (blockIdx.x >> 3);
    const int m0 = sb * 32;
    const int n  = m0 >> 9, l0 = m0 & 511;

    const int b_r    = tid >> 3;
    const int b_slot = (tid & 7) ^ (b_r & 7);
    int boff[4];
    #pragma unroll
    for (int ni = 0; ni < 4; ni++) boff[ni] = (64 * wc + 16 * ni + lr) * 128;
    const int slot0 = ((q4)     ^ (lr & 7)) << 4;
    const int slot1 = ((q4 | 4) ^ (lr & 7)) << 4;

    auto loadB = [&](const u16* __restrict__ Wt, int K, int t, s8v* bv) {
        const int k0 = t * 64;
        const u16* bsrc = Wt + (size_t)b_r * K + k0 + b_slot * 8;
        #pragma unroll
        for (int q = 0; q < 8; q++)
            bv[q] = *(const s8v*)(bsrc + (size_t)q * 32 * K);
    };
    auto writeB = [&](const s8v* bv) {
        #pragma unroll
        for (int q = 0; q < 8; q++)
            *(s8v*)(Bs + q * 4096 + tid * 16) = bv[q];
    };

    for (int u = tid; u < 1728; u += 256) {          // 36 rows x 48 slots
        int j7 = u / 48, s = u - j7 * 48;
        int lp = l0 - 2 + j7;
        f4v v0 = {0.f, 0.f, 0.f, 0.f}, v1 = v0;
        if (lp >= 0 && lp < 512) {
            const float* src = x + ((size_t)((n << 9) + lp)) * 384 + s * 8;
            v0 = *(const f4v*)src;
            v1 = *(const f4v*)(src + 4);
        }
        u16x8 r;
        #pragma unroll
        for (int jj = 0; jj < 4; jj++) { r[jj] = f2bf(v0[jj]); r[4 + jj] = f2bf(v1[jj]); }
        int ss = (s & ~7) | ((s & 7) ^ (j7 & 7));
        *(u16x8*)(LDS + j7 * 768 + ss * 16) = r;
    }

    auto xwread = [&](int j, int s) -> s8v {
        int j7 = min(max(j, 7), 42) - 7;
        int ss = (s & ~7) | ((s & 7) ^ (j7 & 7));
        return *(const s8v*)(LDS + j7 * 768 + (ss << 4));
    };

    // ================= P1: conv1, 18 BK=64 steps ==========================
    f4v acc[3][4];
    #pragma unroll
    for (int mi = 0; mi < 3; mi++)
        #pragma unroll
        for (int ni = 0; ni < 4; ni++) acc[mi][ni] = {0.f, 0.f, 0.f, 0.f};

    {
        s8v bv[8];
        loadB(Wt1, 1152, 0, bv);
        writeB(bv);
    }
    __syncthreads();

    for (int t = 0; t < 18; ++t) {
        s8v nv[8];
        const bool pre = (t + 1 < 18);
        if (pre) loadB(Wt1, 1152, t + 1, nv);
        {
            const int k0 = t * 64;
            const int kc = k0 / 384;
            const int s0 = (k0 - kc * 384) >> 3;
            #pragma unroll
            for (int kk = 0; kk < 2; kk++) {
                const int sl = kk ? slot1 : slot0;
                const int s  = s0 + 4 * kk + q4;
                s8v a0 = xwread(lr + kc,      s);
                s8v a1 = xwread(16 + lr + kc, s);
                s8v a2 = xwread(32 + lr + kc, s);
                s8v b0 = *(const s8v*)(Bs + boff[0] + sl);
                s8v b1 = *(const s8v*)(Bs + boff[1] + sl);
                s8v b2 = *(const s8v*)(Bs + boff[2] + sl);
                s8v b3 = *(const s8v*)(Bs + boff[3] + sl);
                acc[0][0] = __builtin_amdgcn_mfma_f32_16x16x32_bf16(a0, b0, acc[0][0], 0, 0, 0);
                acc[0][1] = __builtin_amdgcn_mfma_f32_16x16x32_bf16(a0, b1, acc[0][1], 0, 0, 0);
                acc[0][2] = __builtin_amdgcn_mfma_f32_16x16x32_bf16(a0, b2, acc[0][2], 0, 0, 0);
                acc[0][3] = __builtin_amdgcn_mfma_f32_16x16x32_bf16(a0, b3, acc[0][3], 0, 0, 0);
                acc[1][0] = __builtin_amdgcn_mfma_f32_16x16x32_bf16(a1, b0, acc[1][0], 0, 0, 0);
                acc[1][1] = __builtin_amdgcn_mfma_f32_16x16x32_bf16(a1, b1, acc[1][1], 0, 0, 0);
                acc[1][2] = __builtin_amdgcn_mfma_f32_16x16x32_bf16(a1, b2, acc[1][2], 0, 0, 0);
                acc[1][3] = __builtin_amdgcn_mfma_f32_16x16x32_bf16(a1, b3, acc[1][3], 0, 0, 0);
                acc[2][0] = __builtin_amdgcn_mfma_f32_16x16x32_bf16(a2, b0, acc[2][0], 0, 0, 0);
                acc[2][1] = __builtin_amdgcn_mfma_f32_16x16x32_bf16(a2, b1, acc[2][1], 0, 0, 0);
                acc[2][2] = __builtin_amdgcn_mfma_f32_16x16x32_bf16(a2, b2, acc[2][2], 0, 0, 0);
                acc[2][3] = __builtin_amdgcn_mfma_f32_16x16x32_bf16(a2, b3, acc[2][3], 0, 0, 0);
            }
        }
        __syncthreads();
        if (pre) {
            writeB(nv);
            __syncthreads();
        }
    }

    // ---- P1 epilogue: bias + LN1 + ReLU -> h1 LDS (34 rows, over xw) ----
    int col[4];
    float cbv[4], gv[4], bbv[4];
    #pragma unroll
    for (int ni = 0; ni < 4; ni++) {
        col[ni] = 64 * wc + 16 * ni + lr;
        cbv[ni] = cb1[col[ni]]; gv[ni] = g1[col[ni]]; bbv[ni] = bb1[col[ni]];
    }

    #pragma unroll
    for (int mi = 0; mi < 3; mi++)
        #pragma unroll
        for (int reg = 0; reg < 4; reg++) {
            float s = 0.f, q = 0.f;
            #pragma unroll
            for (int ni = 0; ni < 4; ni++) {
                float v = acc[mi][ni][reg] + cbv[ni];
                s += v; q += v * v;
            }
            #pragma unroll
            for (int msk = 1; msk < 16; msk <<= 1) {
                s += __shfl_xor(s, msk);
                q += __shfl_xor(q, msk);
            }
            if (lr == 0) {
                int rl = 16 * mi + 4 * q4 + reg;
                redS[rl * 4 + wc] = s;
                redQ[rl * 4 + wc] = q;
            }
        }
    __syncthreads();

    #pragma unroll
    for (int mi = 0; mi < 3; mi++)
        #pragma unroll
        for (int reg = 0; reg < 4; reg++) {
            int rl = 16 * mi + 4 * q4 + reg;
            int h  = rl - 7;
            if (h >= 0 && h < 34) {
                float4 ps = *(float4*)&redS[rl * 4];
                float4 pq = *(float4*)&redQ[rl * 4];
                float mean = (ps.x + ps.y + ps.z + ps.w) * (1.f / 256.f);
                float var  = (pq.x + pq.y + pq.z + pq.w) * (1.f / 256.f) - mean * mean;
                float rs   = rsqrtf(var + 1e-5f);
                int l = l0 - 8 + rl;
                bool lv = (l >= 0 && l < 512);
                #pragma unroll
                for (int ni = 0; ni < 4; ni++) {
                    float v = acc[mi][ni][reg] + cbv[ni];
                    float o = lv ? fmaxf(0.f, (v - mean) * rs * gv[ni] + bbv[ni]) : 0.f;
                    int slot = (col[ni] >> 3) ^ (h & 7);
                    *(u16*)(LDS + h * 512 + slot * 16 + (col[ni] & 7) * 2) = f2bf(o);
                }
            }
        }

    // ================= P2: conv2 (A from h1 LDS), 12 BK=64 steps ==========
    f4v acc2[2][4];
    #pragma unroll
    for (int mi = 0; mi < 2; mi++)
        #pragma unroll
        for (int ni = 0; ni < 4; ni++) acc2[mi][ni] = {0.f, 0.f, 0.f, 0.f};

    {
        s8v bv[8];
        loadB(Wt2, 768, 0, bv);
        writeB(bv);
    }
    __syncthreads();

    for (int t2 = 0; t2 < 12; ++t2) {
        s8v nv[8];
        const bool pre = (t2 + 1 < 12);
        if (pre) loadB(Wt2, 768, t2 + 1, nv);
        {
            const int kc2   = t2 >> 2;
            const int sbase = 8 * (t2 & 3);
            #pragma unroll
            for (int kk = 0; kk < 2; kk++) {
                const int sl = kk ? slot1 : slot0;
                s8v b0 = *(const s8v*)(Bs + boff[0] + sl);
                s8v b1 = *(const s8v*)(Bs + boff[1] + sl);
                s8v b2 = *(const s8v*)(Bs + boff[2] + sl);
                s8v b3 = *(const s8v*)(Bs + boff[3] + sl);
                s8v a0, a1;
                {
                    int h = lr + kc2;
                    int s = sbase + 4 * kk + q4;
                    a0 = *(const s8v*)(LDS + h * 512 + ((s ^ (h & 7)) << 4));
                    h = 16 + lr + kc2;
                    a1 = *(const s8v*)(LDS + h * 512 + ((s ^ (h & 7)) << 4));
                }
                acc2[0][0] = __builtin_amdgcn_mfma_f32_16x16x32_bf16(a0, b0, acc2[0][0], 0, 0, 0);
                acc2[0][1] = __builtin_amdgcn_mfma_f32_16x16x32_bf16(a0, b1, acc2[0][1], 0, 0, 0);
                acc2[0][2] = __builtin_amdgcn_mfma_f32_16x16x32_bf16(a0, b2, acc2[0][2], 0, 0, 0);
                acc2[0][3] = __builtin_amdgcn_mfma_f32_16x16x32_bf16(a0, b3, acc2[0][3], 0, 0, 0);
                acc2[1][0] = __builtin_amdgcn_mfma_f32_16x16x32_bf16(a1, b0, acc2[1][0], 0, 0, 0);
                acc2[1][1] = __builtin_amdgcn_mfma_f32_16x16x32_bf16(a1, b1, acc2[1][1], 0, 0, 0);
                acc2[1][2] = __builtin_amdgcn_mfma_f32_16x16x32_bf16(a1, b2, acc2[1][2], 0, 0, 0);
                acc2[1][3] = __builtin_amdgcn_mfma_f32_16x16x32_bf16(a1, b3, acc2[1][3], 0, 0, 0);
            }
        }
        __syncthreads();
        if (pre) {
            writeB(nv);
            __syncthreads();
        }
    }

    // ---- P2 epilogue: bias + LN2 + ReLU + dot(lin_w) -> dpo ----
    float cbv2[4], gv2[4], bbv2[4], lwv[4];
    #pragma unroll
    for (int ni = 0; ni < 4; ni++) {
        cbv2[ni] = cb2[col[ni]]; gv2[ni] = g2[col[ni]]; bbv2[ni] = bb2[col[ni]];
        lwv[ni]  = lw[col[ni]];
    }

    float sv[2][4], sq[2][4];
    #pragma unroll
    for (int mi = 0; mi < 2; mi++)
        #pragma unroll
        for (int reg = 0; reg < 4; reg++) {
            float s = 0.f, q = 0.f;
            #pragma unroll
            for (int ni = 0; ni < 4; ni++) {
                float v = acc2[mi][ni][reg] + cbv2[ni];
                s += v; q += v * v;
            }
            #pragma unroll
            for (int msk = 1; msk < 16; msk <<= 1) {
                s += __shfl_xor(s, msk);
                q += __shfl_xor(q, msk);
            }
            sv[mi][reg] = s; sq[mi][reg] = q;
        }
    __syncthreads();
    if (lr == 0) {
        #pragma unroll
        for (int mi = 0; mi < 2; mi++)
            #pragma unroll
            for (int reg = 0; reg < 4; reg++) {
                int rl = 16 * mi + 4 * q4 + reg;
                redS[rl * 4 + wc] = sv[mi][reg];
                redQ[rl * 4 + wc] = sq[mi][reg];
            }
    }
    __syncthreads();

    float pp[2][4];
    #pragma unroll
    for (int mi = 0; mi < 2; mi++)
        #pragma unroll
        for (int reg = 0; reg < 4; reg++) {
            int rl = 16 * mi + 4 * q4 + reg;
            float4 ps = *(float4*)&redS[rl * 4];
            float4 pq = *(float4*)&redQ[rl * 4];
            float mean = (ps.x + ps.y + ps.z + ps.w) * (1.f / 256.f);
            float var  = (pq.x + pq.y + pq.z + pq.w) * (1.f / 256.f) - mean * mean;
            float rs   = rsqrtf(var + 1e-5f);
            float p = 0.f;
            #pragma unroll
            for (int ni = 0; ni < 4; ni++) {
                float v = acc2[mi][ni][reg] + cbv2[ni];
                float o = fmaxf(0.f, (v - mean) * rs * gv2[ni] + bbv2[ni]);
                p += o * lwv[ni];
            }
            #pragma unroll
            for (int msk = 1; msk < 16; msk <<= 1) p += __shfl_xor(p, msk);
            pp[mi][reg] = p;
        }
    if (lr == 0) {
        #pragma unroll
        for (int mi = 0; mi < 2; mi++)
            #pragma unroll
            for (int reg = 0; reg < 4; reg++) {
                int rl = 16 * mi + 4 * q4 + reg;
                redP[rl * 4 + wc] = pp[mi][reg];
            }
    }
    __syncthreads();
    if (tid < 32) {
        float4 p4 = *(float4*)&redP[tid * 4];
        dpo[m0 + tid] = p4.x + p4.y + p4.z + p4.w + lbp[0];
    }
}

// ---------------------------------------------------------------------------
extern "C" void kernel_launch(void* const* d_in, const int* in_sizes, int n_in,
                              void* d_out, int out_size, void* d_ws, size_t ws_size,
                              hipStream_t stream) {
    const float* x   = (const float*)d_in[0];
    const float* w1  = (const float*)d_in[1];
    const float* b1  = (const float*)d_in[2];
    const float* g1  = (const float*)d_in[3];
    const float* bb1 = (const float*)d_in[4];
    const float* w2  = (const float*)d_in[5];
    const float* b2  = (const float*)d_in[6];
    const float* g2  = (const float*)d_in[7];
    const float* bb2 = (const float*)d_in[8];
    const float* lw  = (const float*)d_in[9];
    const float* lb  = (const float*)d_in[10];
    const int* target = (const int*)d_in[11];

    // ws layout (bytes): Wt1 589824 | Wt2 393216
    char* wsb = (char*)d_ws;
    u16*  Wt1 = (u16*)wsb;
    u16*  Wt2 = (u16*)(wsb + 589824);

    float* out0 = (float*)d_out;                  // [32, 2048, 384]
    float* dpo  = out0 + (size_t)32 * 2048 * 384; // [32, 512]

    // D1: gather (1024 blocks, XCD-batch grouped) + weight prep
    gather_prep_kernel<<<2944, 256, 0, stream>>>(
        x, target, w1, w2, Wt1, Wt2, out0);

    // D2: fused conv (best-verified structure, R21)
    fused_conv_kernel<<<512, 256, 0, stream>>>(
        x, Wt1, Wt2, b1, g1, bb1, b2, g2, bb2, lw, lb, dpo);
}